// Round 13
// baseline (584.061 us; speedup 1.0000x reference)
//
#include <hip/hip_runtime.h>
#include <hip/hip_fp16.h>
#include <math.h>

// GCNII forward: N=100000, E=1.6M, F_IN=300, H=64, OUT=20, L=8
// Round 13: accum (r9 single-copy) merged with MFMA input GEMM (disjoint
// resource profiles); standalone XCD-binned fill; layer gather unrolled to
// 8 edges/iter with all loads issued ahead of FMAs.

#define HID 64
#define FIN 300
#define NOUT 20
#define ALPHA 0.1f
#define DSCALE 262144.0f   // 2^18 fixed-point scale for weighted degree
#define CNT_SHIFT 25
#define DEG_MASK 0x1FFFFFFu
#define ABLK 2048          // accum blocks inside merged kernel

typedef _Float16 f16;
typedef f16 f16x8 __attribute__((ext_vector_type(8)));
typedef float f32x4 __attribute__((ext_vector_type(4)));

// ---- helpers -----------------------------------------------------------
__device__ __forceinline__ float wdec(unsigned v) {
    union { unsigned short u; __half h; } c;
    c.u = (unsigned short)(v >> 17);
    return __half2float(c.h);
}

__device__ __forceinline__ void unpack8(const float4& v, float* f) {
    const __half2* p = reinterpret_cast<const __half2*>(&v);
#pragma unroll
    for (int i = 0; i < 4; ++i) {
        float2 t = __half22float2(p[i]);
        f[2 * i] = t.x;
        f[2 * i + 1] = t.y;
    }
}

// ---- unpack: dinv + padded counts + per-block sums (wave reduce) -------
__global__ __launch_bounds__(1024) void unpackscan_k(const unsigned* __restrict__ packed,
                                                     float* __restrict__ dinv,
                                                     int* __restrict__ padcnt,
                                                     int* __restrict__ bsum, int n) {
    __shared__ int ws[16];
    int t = threadIdx.x, i = blockIdx.x * 1024 + t;
    int pad = 0;
    if (i < n) {
        unsigned v = packed[i];
        int cnt = (int)(v >> CNT_SHIFT);
        float d = 1.0f + (float)(v & DEG_MASK) * (1.0f / DSCALE);
        dinv[i] = rsqrtf(d);
        pad = (cnt + 3) & ~3;
        padcnt[i] = pad;
    }
    int s = pad;
#pragma unroll
    for (int d = 1; d < 64; d <<= 1) s += __shfl_xor(s, d);
    if ((t & 63) == 0) ws[t >> 6] = s;
    __syncthreads();
    if (t == 0) {
        int tot = 0;
#pragma unroll
        for (int k = 0; k < 16; ++k) tot += ws[k];
        bsum[blockIdx.x] = tot;
    }
}

// ---- wave-parallel exclusive scan of block sums (nb <= 128) -----------
__global__ void scan2_k(int* __restrict__ bsum, int nb, int* __restrict__ rp, int n) {
    int lane = threadIdx.x;  // 64 threads
    int acc = 0;
    for (int base = 0; base < nb; base += 64) {
        int idx = base + lane;
        int orig = (idx < nb) ? bsum[idx] : 0;
        int v = orig;
#pragma unroll
        for (int d = 1; d < 64; d <<= 1) {
            int u = __shfl_up(v, d);
            if (lane >= d) v += u;
        }
        if (idx < nb) bsum[idx] = acc + v - orig;
        acc += __shfl(v, 63);
    }
    if (lane == 0) rp[n] = acc;
}

// ---- per-element exclusive scan -> rp (wave scan + LDS) ---------------
__global__ __launch_bounds__(1024) void scan3_k(const int* __restrict__ padcnt,
                                                const int* __restrict__ bsum,
                                                int* __restrict__ rp, int n) {
    __shared__ int ws[16];
    int t = threadIdx.x, i = blockIdx.x * 1024 + t;
    int lane = t & 63, w = t >> 6;
    int v = (i < n) ? padcnt[i] : 0;
    int sv = v;
#pragma unroll
    for (int d = 1; d < 64; d <<= 1) {
        int u = __shfl_up(sv, d);
        if (lane >= d) sv += u;
    }
    if (lane == 63) ws[w] = sv;
    __syncthreads();
    if (w == 0) {
        int x = (lane < 16) ? ws[lane] : 0;
#pragma unroll
        for (int d = 1; d < 16; d <<= 1) {
            int u = __shfl_up(x, d);
            if (lane >= d) x += u;
        }
        if (lane < 16) ws[lane] = x;
    }
    __syncthreads();
    int woff = (w > 0) ? ws[w - 1] : 0;
    if (i < n) rp[i] = bsum[blockIdx.x] + woff + sv - v;
}

// ---- fill CSR: XCD-binned, streams packed records, no atomics ---------
__global__ __launch_bounds__(256) void fill_k(const uint2* __restrict__ rec,
                                              const float* __restrict__ dinv,
                                              const int* __restrict__ rp,
                                              unsigned* __restrict__ edges,
                                              int e, int n) {
    int xcd = blockIdx.x & 7;
    int lo = (int)(((long long)n * xcd) >> 3);
    int hi = (int)(((long long)n * (xcd + 1)) >> 3);
    int nblk = gridDim.x >> 3;
    int stride = nblk * 256;
    for (int i = (blockIdx.x >> 3) * 256 + threadIdx.x; i < e; i += stride) {
        uint2 rc = rec[i];
        int c = (int)(rc.x & 0x1FFFFu);
        if (c < lo || c >= hi) continue;
        int r = (int)(rc.y & 0x1FFFFu);
        union { unsigned short u; __half h; } ev;
        ev.u = (unsigned short)(rc.y >> 17);
        float nw = (1.0f - ALPHA) * dinv[r] * __half2float(ev.h) * dinv[c];
        union { __half h; unsigned short u; } cv;
        cv.h = __float2half(nw);
        int rank = (int)((rc.x >> 17) & 0x7Fu);
        edges[rp[c] + rank] = ((unsigned)cv.u << 17) | (unsigned)r;
    }
}

// ---- W^T fp16 precompute for input GEMM (padded K=320) ----------------
__global__ void wt_k(const float* __restrict__ Win, f16* __restrict__ Wt) {
    int i = blockIdx.x * blockDim.x + threadIdx.x;  // 64*320
    if (i < 64 * 320) {
        int c = i / 320, k = i - c * 320;
        Wt[i] = (k < FIN) ? (f16)Win[k * 64 + c] : (f16)0.0f;
    }
}

// ---- merged: blocks [0,ABLK) accum histogram; rest MFMA input GEMM -----
__global__ __launch_bounds__(256) void agi_k(const int* __restrict__ row,
                                             const int* __restrict__ col,
                                             const float* __restrict__ ew,
                                             unsigned* __restrict__ packed,
                                             uint2* __restrict__ rec, int e,
                                             const float* __restrict__ x,
                                             const f16* __restrict__ Wt,
                                             const float* __restrict__ bin,
                                             __half* __restrict__ x0h, int n) {
    __shared__ f16 As[64 * 72];
    int t = threadIdx.x;
    if (blockIdx.x < ABLK) {
        // ------- accum path: one 32-bit atomic per edge + rec write -------
        for (int i = blockIdx.x * 256 + t; i < e; i += ABLK * 256) {
            int c = col[i], r = row[i];
            float wv = ew[i];
            unsigned q = (unsigned)__float2uint_rn(wv * DSCALE);
            unsigned old = atomicAdd(&packed[c], (1u << CNT_SHIFT) | q);
            unsigned rank = (old >> CNT_SHIFT) & 0x7Fu;
            union { __half h; unsigned short u; } cv;
            cv.h = __float2half(wv);  // w in [0,1) -> bit15 == 0
            rec[i] = make_uint2((unsigned)c | (rank << 17),
                                (unsigned)r | ((unsigned)cv.u << 17));
        }
        return;
    }
    // ------- input GEMM path (reg-staged double buffer + MFMA) -------
    int lane = t & 63, wv = t >> 6;
    int node0 = (blockIdx.x - ABLK) * 64;
    int lr = lane & 15, kg = lane >> 4;
    int fi = t & 15, rowbase = t >> 4;
    f32x4 acc0 = {0, 0, 0, 0}, acc1 = {0, 0, 0, 0}, acc2 = {0, 0, 0, 0}, acc3 = {0, 0, 0, 0};
    float4 xr[4];
    auto loadchunk = [&](int c) {
#pragma unroll
        for (int it = 0; it < 4; ++it) {
            int rw = rowbase + it * 16;
            int rr = node0 + rw;
            rr = (rr < n) ? rr : (n - 1);
            int kbase = c * 64 + fi * 4;
            xr[it] = make_float4(0.f, 0.f, 0.f, 0.f);
            if (kbase < FIN)
                xr[it] = *reinterpret_cast<const float4*>(x + (size_t)rr * FIN + kbase);
        }
    };
    loadchunk(0);
    for (int c = 0; c < 5; ++c) {
        __syncthreads();
#pragma unroll
        for (int it = 0; it < 4; ++it) {
            int rw = rowbase + it * 16;
            union { float2 f2; f16 h[4]; } u;
            u.h[0] = (f16)xr[it].x; u.h[1] = (f16)xr[it].y;
            u.h[2] = (f16)xr[it].z; u.h[3] = (f16)xr[it].w;
            *reinterpret_cast<float2*>(As + rw * 72 + fi * 4) = u.f2;
        }
        __syncthreads();
        if (c < 4) loadchunk(c + 1);
#pragma unroll
        for (int ks = 0; ks < 2; ++ks) {
            f16x8 a = *(const f16x8*)(As + (wv * 16 + lr) * 72 + ks * 32 + kg * 8);
            const f16* wb = Wt + c * 64 + ks * 32 + kg * 8;
            f16x8 b0 = *(const f16x8*)(wb + (0 * 16 + lr) * 320);
            f16x8 b1 = *(const f16x8*)(wb + (1 * 16 + lr) * 320);
            f16x8 b2 = *(const f16x8*)(wb + (2 * 16 + lr) * 320);
            f16x8 b3 = *(const f16x8*)(wb + (3 * 16 + lr) * 320);
            acc0 = __builtin_amdgcn_mfma_f32_16x16x32_f16(a, b0, acc0, 0, 0, 0);
            acc1 = __builtin_amdgcn_mfma_f32_16x16x32_f16(a, b1, acc1, 0, 0, 0);
            acc2 = __builtin_amdgcn_mfma_f32_16x16x32_f16(a, b2, acc2, 0, 0, 0);
            acc3 = __builtin_amdgcn_mfma_f32_16x16x32_f16(a, b3, acc3, 0, 0, 0);
        }
    }
    float bi0 = bin[0 * 16 + lr], bi1 = bin[1 * 16 + lr];
    float bi2 = bin[2 * 16 + lr], bi3 = bin[3 * 16 + lr];
    f16 ov[4][4];
#pragma unroll
    for (int r = 0; r < 4; ++r) {
        ov[0][r] = (f16)fmaxf(acc0[r] + bi0, 0.f);
        ov[1][r] = (f16)fmaxf(acc1[r] + bi1, 0.f);
        ov[2][r] = (f16)fmaxf(acc2[r] + bi2, 0.f);
        ov[3][r] = (f16)fmaxf(acc3[r] + bi3, 0.f);
    }
    __syncthreads();
#pragma unroll
    for (int cg = 0; cg < 4; ++cg)
#pragma unroll
        for (int r = 0; r < 4; ++r)
            As[(wv * 16 + kg * 4 + r) * 72 + cg * 16 + lr] = ov[cg][r];
    __syncthreads();
#pragma unroll
    for (int it = 0; it < 2; ++it) {
        int idx = t + it * 256;
        int rw = idx >> 3, ch = idx & 7;
        int node = node0 + rw;
        if (node < n)
            ((float4*)(x0h + (size_t)node * 64))[ch] =
                *reinterpret_cast<const float4*>(As + rw * 72 + ch * 8);
    }
}

// ---- fused layer: 8-edge-deep gather -> LDS z -> MFMA (+fused out) -----
__global__ __launch_bounds__(256) void layer_k(const int* __restrict__ rp,
                                               const unsigned* __restrict__ edges,
                                               const float* __restrict__ dinv,
                                               const __half* __restrict__ x0h,
                                               const __half* __restrict__ hin,
                                               __half* __restrict__ hout,
                                               const float* __restrict__ Wl,
                                               float beta, int n,
                                               const float* __restrict__ Wout,
                                               const float* __restrict__ bout,
                                               float* __restrict__ out) {
    __shared__ f16 As[64 * 72];  // z tile / h tile
    __shared__ f16 Bs[64 * 72];  // W^T tile (reused for Wout^T)
    int t = threadIdx.x, lane = t & 63, wv = t >> 6;
    int node0 = blockIdx.x * 64;
    for (int i = t; i < 4096; i += 256) {
        int k = i >> 6, c = i & 63;
        Bs[c * 72 + k] = (f16)Wl[i];
    }
    int g = lane >> 3, c8 = lane & 7;
#pragma unroll
    for (int pass = 0; pass < 2; ++pass) {
        int row = pass * 32 + wv * 8 + g;
        int node = node0 + row;
        int nd = (node < n) ? node : (n - 1);
        int j = rp[nd], end = (node < n) ? rp[nd + 1] : j;
        float a0[8], a1[8], a2[8], a3[8];
#pragma unroll
        for (int i = 0; i < 8; ++i) { a0[i] = 0.f; a1[i] = 0.f; a2[i] = 0.f; a3[i] = 0.f; }
        while (__any(j < end)) {
            bool va = j < end;
            bool vb = (j + 4) < end;
            uint4 ea, eb;
            float4 ra0, ra1, ra2, ra3, rb0, rb1, rb2, rb3;
            // issue both edge-word loads first
            if (va) ea = *reinterpret_cast<const uint4*>(edges + j);
            if (vb) eb = *reinterpret_cast<const uint4*>(edges + j + 4);
            // then all 8 row gathers (no FMA between -> stay in flight)
            if (va) {
                ra0 = ((const float4*)(hin + (size_t)(ea.x & 0x1FFFF) * 64))[c8];
                ra1 = ((const float4*)(hin + (size_t)(ea.y & 0x1FFFF) * 64))[c8];
                ra2 = ((const float4*)(hin + (size_t)(ea.z & 0x1FFFF) * 64))[c8];
                ra3 = ((const float4*)(hin + (size_t)(ea.w & 0x1FFFF) * 64))[c8];
            }
            if (vb) {
                rb0 = ((const float4*)(hin + (size_t)(eb.x & 0x1FFFF) * 64))[c8];
                rb1 = ((const float4*)(hin + (size_t)(eb.y & 0x1FFFF) * 64))[c8];
                rb2 = ((const float4*)(hin + (size_t)(eb.z & 0x1FFFF) * 64))[c8];
                rb3 = ((const float4*)(hin + (size_t)(eb.w & 0x1FFFF) * 64))[c8];
            }
            if (va) {
                float w0 = wdec(ea.x), w1 = wdec(ea.y), w2 = wdec(ea.z), w3 = wdec(ea.w);
                float f0[8], f1[8], f2[8], f3[8];
                unpack8(ra0, f0); unpack8(ra1, f1); unpack8(ra2, f2); unpack8(ra3, f3);
#pragma unroll
                for (int i = 0; i < 8; ++i) {
                    a0[i] = fmaf(w0, f0[i], a0[i]);
                    a1[i] = fmaf(w1, f1[i], a1[i]);
                    a2[i] = fmaf(w2, f2[i], a2[i]);
                    a3[i] = fmaf(w3, f3[i], a3[i]);
                }
            }
            if (vb) {
                float w0 = wdec(eb.x), w1 = wdec(eb.y), w2 = wdec(eb.z), w3 = wdec(eb.w);
                float f0[8], f1[8], f2[8], f3[8];
                unpack8(rb0, f0); unpack8(rb1, f1); unpack8(rb2, f2); unpack8(rb3, f3);
#pragma unroll
                for (int i = 0; i < 8; ++i) {
                    a0[i] = fmaf(w0, f0[i], a0[i]);
                    a1[i] = fmaf(w1, f1[i], a1[i]);
                    a2[i] = fmaf(w2, f2[i], a2[i]);
                    a3[i] = fmaf(w3, f3[i], a3[i]);
                }
            }
            j += 8;
        }
        float di = dinv[nd];
        float c1 = (1.0f - ALPHA) * di * di;
        float4 hs4 = ((const float4*)(hin + (size_t)nd * 64))[c8];
        float4 xs4 = ((const float4*)(x0h + (size_t)nd * 64))[c8];
        float hf[8], xf[8];
        unpack8(hs4, hf);
        unpack8(xs4, xf);
        f16x8 zv8;
#pragma unroll
        for (int i = 0; i < 8; ++i)
            zv8[i] = (f16)fmaf(ALPHA, xf[i],
                               fmaf(c1, hf[i], (a0[i] + a1[i]) + (a2[i] + a3[i])));
        *(f16x8*)(As + row * 72 + c8 * 8) = zv8;
    }
    __syncthreads();
    int lr = lane & 15, kg = lane >> 4;
    f32x4 acc0 = {0, 0, 0, 0}, acc1 = {0, 0, 0, 0}, acc2 = {0, 0, 0, 0}, acc3 = {0, 0, 0, 0};
    f16x8 af0 = *(const f16x8*)(As + (wv * 16 + lr) * 72 + kg * 8);
    f16x8 af1 = *(const f16x8*)(As + (wv * 16 + lr) * 72 + 32 + kg * 8);
    {
        f16x8 b0 = *(const f16x8*)(Bs + (0 * 16 + lr) * 72 + kg * 8);
        f16x8 b1 = *(const f16x8*)(Bs + (0 * 16 + lr) * 72 + 32 + kg * 8);
        acc0 = __builtin_amdgcn_mfma_f32_16x16x32_f16(af0, b0, acc0, 0, 0, 0);
        acc0 = __builtin_amdgcn_mfma_f32_16x16x32_f16(af1, b1, acc0, 0, 0, 0);
    }
    {
        f16x8 b0 = *(const f16x8*)(Bs + (1 * 16 + lr) * 72 + kg * 8);
        f16x8 b1 = *(const f16x8*)(Bs + (1 * 16 + lr) * 72 + 32 + kg * 8);
        acc1 = __builtin_amdgcn_mfma_f32_16x16x32_f16(af0, b0, acc1, 0, 0, 0);
        acc1 = __builtin_amdgcn_mfma_f32_16x16x32_f16(af1, b1, acc1, 0, 0, 0);
    }
    {
        f16x8 b0 = *(const f16x8*)(Bs + (2 * 16 + lr) * 72 + kg * 8);
        f16x8 b1 = *(const f16x8*)(Bs + (2 * 16 + lr) * 72 + 32 + kg * 8);
        acc2 = __builtin_amdgcn_mfma_f32_16x16x32_f16(af0, b0, acc2, 0, 0, 0);
        acc2 = __builtin_amdgcn_mfma_f32_16x16x32_f16(af1, b1, acc2, 0, 0, 0);
    }
    {
        f16x8 b0 = *(const f16x8*)(Bs + (3 * 16 + lr) * 72 + kg * 8);
        f16x8 b1 = *(const f16x8*)(Bs + (3 * 16 + lr) * 72 + 32 + kg * 8);
        acc3 = __builtin_amdgcn_mfma_f32_16x16x32_f16(af0, b0, acc3, 0, 0, 0);
        acc3 = __builtin_amdgcn_mfma_f32_16x16x32_f16(af1, b1, acc3, 0, 0, 0);
    }
    float omb = 1.0f - beta;
    f16 ov[4][4];
#pragma unroll
    for (int cg = 0; cg < 4; ++cg) {
        f32x4 acc = (cg == 0) ? acc0 : (cg == 1) ? acc1 : (cg == 2) ? acc2 : acc3;
        int col = cg * 16 + lr;
#pragma unroll
        for (int r = 0; r < 4; ++r) {
            float zv = (float)As[(wv * 16 + kg * 4 + r) * 72 + col];
            ov[cg][r] = (f16)fmaxf(fmaf(beta, acc[r], omb * zv), 0.f);
        }
    }
    __syncthreads();
#pragma unroll
    for (int cg = 0; cg < 4; ++cg)
#pragma unroll
        for (int r = 0; r < 4; ++r)
            As[(wv * 16 + kg * 4 + r) * 72 + cg * 16 + lr] = ov[cg][r];
    __syncthreads();

    if (!Wout) {
#pragma unroll
        for (int it = 0; it < 2; ++it) {
            int idx = t + it * 256;
            int row = idx >> 3, ch = idx & 7;
            int node = node0 + row;
            if (node < n)
                ((float4*)(hout + (size_t)node * 64))[ch] =
                    *reinterpret_cast<const float4*>(As + row * 72 + ch * 8);
        }
    } else {
        // last layer: fused out = h @ W_out + b_out via second MFMA pass
        for (int i = t; i < 32 * 64; i += 256) {
            int c = i >> 6, k = i & 63;
            Bs[c * 72 + k] = (c < NOUT) ? (f16)Wout[k * NOUT + c] : (f16)0.0f;
        }
        __syncthreads();
        f16x8 ha0 = *(const f16x8*)(As + (wv * 16 + lr) * 72 + kg * 8);
        f16x8 ha1 = *(const f16x8*)(As + (wv * 16 + lr) * 72 + 32 + kg * 8);
#pragma unroll
        for (int ct = 0; ct < 2; ++ct) {
            f32x4 oacc = {0, 0, 0, 0};
            f16x8 b0 = *(const f16x8*)(Bs + (ct * 16 + lr) * 72 + kg * 8);
            f16x8 b1 = *(const f16x8*)(Bs + (ct * 16 + lr) * 72 + 32 + kg * 8);
            oacc = __builtin_amdgcn_mfma_f32_16x16x32_f16(ha0, b0, oacc, 0, 0, 0);
            oacc = __builtin_amdgcn_mfma_f32_16x16x32_f16(ha1, b1, oacc, 0, 0, 0);
            int col = ct * 16 + lr;
            if (col < NOUT) {
                float bo = bout[col];
#pragma unroll
                for (int r = 0; r < 4; ++r) {
                    int nd2 = node0 + wv * 16 + kg * 4 + r;
                    if (nd2 < n) out[(size_t)nd2 * NOUT + col] = oacc[r] + bo;
                }
            }
        }
    }
}

extern "C" void kernel_launch(void* const* d_in, const int* in_sizes, int n_in,
                              void* d_out, int out_size, void* d_ws, size_t ws_size,
                              hipStream_t stream) {
    const float* x    = (const float*)d_in[0];
    const int*   ei   = (const int*)d_in[1];
    const float* ew   = (const float*)d_in[2];
    const float* Win  = (const float*)d_in[3];
    const float* bin  = (const float*)d_in[4];
    const float* cw   = (const float*)d_in[5];
    const float* Wout = (const float*)d_in[6];
    const float* bout = (const float*)d_in[7];

    const int n = in_sizes[0] / FIN;          // 100000
    const int e = in_sizes[2];                // 1600000
    const int L = in_sizes[5] / (HID * HID);  // 8
    const int* row = ei;
    const int* col = ei + e;
    const int epadmax = e + 3 * n + 64;

    size_t off = 0;
    auto alloc = [&](size_t bytes) -> char* {
        char* q = (char*)d_ws + off;
        off = (off + bytes + 255) & ~(size_t)255;
        return q;
    };
    __half* x0h  = (__half*)alloc((size_t)n * HID * 2);
    __half* hA   = (__half*)alloc((size_t)n * HID * 2);
    __half* hB   = (__half*)alloc((size_t)n * HID * 2);
    unsigned* edges = (unsigned*)alloc((size_t)epadmax * 4);
    uint2* rec   = (uint2*)alloc((size_t)e * 8);
    unsigned* packed = (unsigned*)alloc((size_t)n * 4);
    float* dinv  = (float*)alloc((size_t)n * 4);
    int*   padcnt= (int*)alloc((size_t)n * 4);
    int*   rp    = (int*)alloc((size_t)(n + 1) * 4);
    int*   bsum  = (int*)alloc(1024 * 4);
    f16*   Wt    = (f16*)alloc((size_t)64 * 320 * 2);

    const int nb = (n + 1023) / 1024;
    const int ntile = (n + 63) / 64;

    hipMemsetAsync(packed, 0, (size_t)n * 4, stream);
    hipMemsetAsync(edges, 0, (size_t)epadmax * 4, stream);
    wt_k<<<(64 * 320 + 255) / 256, 256, 0, stream>>>(Win, Wt);

    agi_k<<<ABLK + ntile, 256, 0, stream>>>(row, col, ew, packed, rec, e,
                                            x, Wt, bin, x0h, n);
    unpackscan_k<<<nb, 1024, 0, stream>>>(packed, dinv, padcnt, bsum, n);
    scan2_k<<<1, 64, 0, stream>>>(bsum, nb, rp, n);
    scan3_k<<<nb, 1024, 0, stream>>>(padcnt, bsum, rp, n);
    fill_k<<<1024, 256, 0, stream>>>(rec, dinv, rp, edges, e, n);

    const __half* hin = x0h;
    __half* hout = hA;
    for (int l = 0; l < L; ++l) {
        float beta = (float)log(0.5 / (double)(l + 1) + 1.0);
        bool last = (l == L - 1);
        layer_k<<<ntile, 256, 0, stream>>>(rp, edges, dinv, x0h, hin, hout,
                                           cw + (size_t)l * HID * HID, beta, n,
                                           last ? Wout : nullptr,
                                           last ? bout : nullptr,
                                           last ? (float*)d_out : nullptr);
        hin = hout;
        hout = (hout == hA) ? hB : hA;
    }
}

// Round 14
// 481.533 us; speedup vs baseline: 1.2129x; 1.2129x over previous
//
#include <hip/hip_runtime.h>
#include <hip/hip_fp16.h>
#include <math.h>

// GCNII forward: N=100000, E=1.6M, F_IN=300, H=64, OUT=20, L=8
// Round 14: recombination of measured-best components — r9 single-copy
// accum, r12 fill+gemm_in merged kernel, r9 4-edge masked-gather layer,
// pad-slot zeroing folded into scan3 (no big edges memset).

#define HID 64
#define FIN 300
#define NOUT 20
#define ALPHA 0.1f
#define DSCALE 262144.0f   // 2^18 fixed-point scale for weighted degree
#define CNT_SHIFT 25
#define DEG_MASK 0x1FFFFFFu
#define FBLK 1024          // fill blocks inside merged kernel

typedef _Float16 f16;
typedef f16 f16x8 __attribute__((ext_vector_type(8)));
typedef float f32x4 __attribute__((ext_vector_type(4)));

// ---- helpers -----------------------------------------------------------
__device__ __forceinline__ float wdec(unsigned v) {
    union { unsigned short u; __half h; } c;
    c.u = (unsigned short)(v >> 17);
    return __half2float(c.h);
}

__device__ __forceinline__ void unpack8(const float4& v, float* f) {
    const __half2* p = reinterpret_cast<const __half2*>(&v);
#pragma unroll
    for (int i = 0; i < 4; ++i) {
        float2 t = __half22float2(p[i]);
        f[2 * i] = t.x;
        f[2 * i + 1] = t.y;
    }
}

// ---- histogram: one 32-bit atomic per edge + packed record (r9) --------
__global__ void accum_k(const int* __restrict__ row, const int* __restrict__ col,
                        const float* __restrict__ ew,
                        unsigned* __restrict__ packed,
                        uint2* __restrict__ rec, int e) {
    int i = blockIdx.x * blockDim.x + threadIdx.x;
    if (i < e) {
        int c = col[i], r = row[i];
        float wv = ew[i];
        unsigned q = (unsigned)__float2uint_rn(wv * DSCALE);
        unsigned old = atomicAdd(&packed[c], (1u << CNT_SHIFT) | q);
        unsigned rank = (old >> CNT_SHIFT) & 0x7Fu;
        union { __half h; unsigned short u; } cv;
        cv.h = __float2half(wv);  // w in [0,1) -> bit15 == 0
        rec[i] = make_uint2((unsigned)c | (rank << 17),
                            (unsigned)r | ((unsigned)cv.u << 17));
    }
}

// ---- unpack: dinv + padded counts + per-block sums (wave reduce) -------
__global__ __launch_bounds__(1024) void unpackscan_k(const unsigned* __restrict__ packed,
                                                     float* __restrict__ dinv,
                                                     int* __restrict__ padcnt,
                                                     int* __restrict__ bsum, int n) {
    __shared__ int ws[16];
    int t = threadIdx.x, i = blockIdx.x * 1024 + t;
    int pad = 0;
    if (i < n) {
        unsigned v = packed[i];
        int cnt = (int)(v >> CNT_SHIFT);
        float d = 1.0f + (float)(v & DEG_MASK) * (1.0f / DSCALE);
        dinv[i] = rsqrtf(d);
        pad = (cnt + 3) & ~3;
        padcnt[i] = pad;
    }
    int s = pad;
#pragma unroll
    for (int d = 1; d < 64; d <<= 1) s += __shfl_xor(s, d);
    if ((t & 63) == 0) ws[t >> 6] = s;
    __syncthreads();
    if (t == 0) {
        int tot = 0;
#pragma unroll
        for (int k = 0; k < 16; ++k) tot += ws[k];
        bsum[blockIdx.x] = tot;
    }
}

// ---- wave-parallel exclusive scan of block sums (nb <= 128) -----------
__global__ void scan2_k(int* __restrict__ bsum, int nb, int* __restrict__ rp, int n) {
    int lane = threadIdx.x;  // 64 threads
    int acc = 0;
    for (int base = 0; base < nb; base += 64) {
        int idx = base + lane;
        int orig = (idx < nb) ? bsum[idx] : 0;
        int v = orig;
#pragma unroll
        for (int d = 1; d < 64; d <<= 1) {
            int u = __shfl_up(v, d);
            if (lane >= d) v += u;
        }
        if (idx < nb) bsum[idx] = acc + v - orig;
        acc += __shfl(v, 63);
    }
    if (lane == 0) rp[n] = acc;
}

// ---- per-element scan -> rp; zero the <=3 pad slots of edges ----------
__global__ __launch_bounds__(1024) void scan3_k(const int* __restrict__ padcnt,
                                                const unsigned* __restrict__ packed,
                                                const int* __restrict__ bsum,
                                                int* __restrict__ rp,
                                                unsigned* __restrict__ edges, int n) {
    __shared__ int ws[16];
    int t = threadIdx.x, i = blockIdx.x * 1024 + t;
    int lane = t & 63, w = t >> 6;
    int v = (i < n) ? padcnt[i] : 0;
    int sv = v;
#pragma unroll
    for (int d = 1; d < 64; d <<= 1) {
        int u = __shfl_up(sv, d);
        if (lane >= d) sv += u;
    }
    if (lane == 63) ws[w] = sv;
    __syncthreads();
    if (w == 0) {
        int x = (lane < 16) ? ws[lane] : 0;
#pragma unroll
        for (int d = 1; d < 16; d <<= 1) {
            int u = __shfl_up(x, d);
            if (lane >= d) x += u;
        }
        if (lane < 16) ws[lane] = x;
    }
    __syncthreads();
    int woff = (w > 0) ? ws[w - 1] : 0;
    if (i < n) {
        int base = bsum[blockIdx.x] + woff + sv - v;
        rp[i] = base;
        int cnt = (int)(packed[i] >> CNT_SHIFT);
        for (int k = cnt; k < v; ++k) edges[base + k] = 0u;  // pad slots -> 0
    }
}

// ---- W^T fp16 precompute for input GEMM (padded K=320) ----------------
__global__ void wt_k(const float* __restrict__ Win, f16* __restrict__ Wt) {
    int i = blockIdx.x * blockDim.x + threadIdx.x;  // 64*320
    if (i < 64 * 320) {
        int c = i / 320, k = i - c * 320;
        Wt[i] = (k < FIN) ? (f16)Win[k * 64 + c] : (f16)0.0f;
    }
}

// ---- merged: blocks [0,FBLK) fill CSR; blocks [FBLK,..) input GEMM -----
__global__ __launch_bounds__(256) void fgi_k(const uint2* __restrict__ rec,
                                             const float* __restrict__ dinv,
                                             const int* __restrict__ rp,
                                             unsigned* __restrict__ edges, int e,
                                             const float* __restrict__ x,
                                             const f16* __restrict__ Wt,
                                             const float* __restrict__ bin,
                                             __half* __restrict__ x0h, int n) {
    __shared__ f16 As[64 * 72];
    int t = threadIdx.x;
    if (blockIdx.x < FBLK) {
        // ------- fill path (XCD-binned, no atomics) -------
        int xcd = blockIdx.x & 7;
        int lo = (int)(((long long)n * xcd) >> 3);
        int hi = (int)(((long long)n * (xcd + 1)) >> 3);
        int stride = (FBLK >> 3) * 256;
        for (int i = (blockIdx.x >> 3) * 256 + t; i < e; i += stride) {
            uint2 rc = rec[i];
            int c = (int)(rc.x & 0x1FFFFu);
            if (c < lo || c >= hi) continue;
            int r = (int)(rc.y & 0x1FFFFu);
            union { unsigned short u; __half h; } ev;
            ev.u = (unsigned short)(rc.y >> 17);
            float nw = (1.0f - ALPHA) * dinv[r] * __half2float(ev.h) * dinv[c];
            union { __half h; unsigned short u; } cv;
            cv.h = __float2half(nw);
            int rank = (int)((rc.x >> 17) & 0x7Fu);
            edges[rp[c] + rank] = ((unsigned)cv.u << 17) | (unsigned)r;
        }
        return;
    }
    // ------- input GEMM path (reg-staged double buffer + MFMA) -------
    int lane = t & 63, wv = t >> 6;
    int node0 = (blockIdx.x - FBLK) * 64;
    int lr = lane & 15, kg = lane >> 4;
    int fi = t & 15, rowbase = t >> 4;
    f32x4 acc0 = {0, 0, 0, 0}, acc1 = {0, 0, 0, 0}, acc2 = {0, 0, 0, 0}, acc3 = {0, 0, 0, 0};
    float4 xr[4];
    auto loadchunk = [&](int c) {
#pragma unroll
        for (int it = 0; it < 4; ++it) {
            int rw = rowbase + it * 16;
            int rr = node0 + rw;
            rr = (rr < n) ? rr : (n - 1);
            int kbase = c * 64 + fi * 4;
            xr[it] = make_float4(0.f, 0.f, 0.f, 0.f);
            if (kbase < FIN)
                xr[it] = *reinterpret_cast<const float4*>(x + (size_t)rr * FIN + kbase);
        }
    };
    loadchunk(0);
    for (int c = 0; c < 5; ++c) {
        __syncthreads();
#pragma unroll
        for (int it = 0; it < 4; ++it) {
            int rw = rowbase + it * 16;
            union { float2 f2; f16 h[4]; } u;
            u.h[0] = (f16)xr[it].x; u.h[1] = (f16)xr[it].y;
            u.h[2] = (f16)xr[it].z; u.h[3] = (f16)xr[it].w;
            *reinterpret_cast<float2*>(As + rw * 72 + fi * 4) = u.f2;
        }
        __syncthreads();
        if (c < 4) loadchunk(c + 1);
#pragma unroll
        for (int ks = 0; ks < 2; ++ks) {
            f16x8 a = *(const f16x8*)(As + (wv * 16 + lr) * 72 + ks * 32 + kg * 8);
            const f16* wb = Wt + c * 64 + ks * 32 + kg * 8;
            f16x8 b0 = *(const f16x8*)(wb + (0 * 16 + lr) * 320);
            f16x8 b1 = *(const f16x8*)(wb + (1 * 16 + lr) * 320);
            f16x8 b2 = *(const f16x8*)(wb + (2 * 16 + lr) * 320);
            f16x8 b3 = *(const f16x8*)(wb + (3 * 16 + lr) * 320);
            acc0 = __builtin_amdgcn_mfma_f32_16x16x32_f16(a, b0, acc0, 0, 0, 0);
            acc1 = __builtin_amdgcn_mfma_f32_16x16x32_f16(a, b1, acc1, 0, 0, 0);
            acc2 = __builtin_amdgcn_mfma_f32_16x16x32_f16(a, b2, acc2, 0, 0, 0);
            acc3 = __builtin_amdgcn_mfma_f32_16x16x32_f16(a, b3, acc3, 0, 0, 0);
        }
    }
    float bi0 = bin[0 * 16 + lr], bi1 = bin[1 * 16 + lr];
    float bi2 = bin[2 * 16 + lr], bi3 = bin[3 * 16 + lr];
    f16 ov[4][4];
#pragma unroll
    for (int r = 0; r < 4; ++r) {
        ov[0][r] = (f16)fmaxf(acc0[r] + bi0, 0.f);
        ov[1][r] = (f16)fmaxf(acc1[r] + bi1, 0.f);
        ov[2][r] = (f16)fmaxf(acc2[r] + bi2, 0.f);
        ov[3][r] = (f16)fmaxf(acc3[r] + bi3, 0.f);
    }
    __syncthreads();
#pragma unroll
    for (int cg = 0; cg < 4; ++cg)
#pragma unroll
        for (int r = 0; r < 4; ++r)
            As[(wv * 16 + kg * 4 + r) * 72 + cg * 16 + lr] = ov[cg][r];
    __syncthreads();
#pragma unroll
    for (int it = 0; it < 2; ++it) {
        int idx = t + it * 256;
        int rw = idx >> 3, ch = idx & 7;
        int node = node0 + rw;
        if (node < n)
            ((float4*)(x0h + (size_t)node * 64))[ch] =
                *reinterpret_cast<const float4*>(As + rw * 72 + ch * 8);
    }
}

// ---- fused layer: masked uint4 gather -> LDS z -> MFMA (+fused out) ----
__global__ __launch_bounds__(256) void layer_k(const int* __restrict__ rp,
                                               const unsigned* __restrict__ edges,
                                               const float* __restrict__ dinv,
                                               const __half* __restrict__ x0h,
                                               const __half* __restrict__ hin,
                                               __half* __restrict__ hout,
                                               const float* __restrict__ Wl,
                                               float beta, int n,
                                               const float* __restrict__ Wout,
                                               const float* __restrict__ bout,
                                               float* __restrict__ out) {
    __shared__ f16 As[64 * 72];  // z tile / h tile
    __shared__ f16 Bs[64 * 72];  // W^T tile (reused for Wout^T)
    int t = threadIdx.x, lane = t & 63, wv = t >> 6;
    int node0 = blockIdx.x * 64;
    for (int i = t; i < 4096; i += 256) {
        int k = i >> 6, c = i & 63;
        Bs[c * 72 + k] = (f16)Wl[i];
    }
    int g = lane >> 3, c8 = lane & 7;
#pragma unroll
    for (int pass = 0; pass < 2; ++pass) {
        int row = pass * 32 + wv * 8 + g;
        int node = node0 + row;
        int nd = (node < n) ? node : (n - 1);
        int j = rp[nd], end = (node < n) ? rp[nd + 1] : j;
        float a0[8], a1[8], a2[8], a3[8];
#pragma unroll
        for (int i = 0; i < 8; ++i) { a0[i] = 0.f; a1[i] = 0.f; a2[i] = 0.f; a3[i] = 0.f; }
        while (__any(j < end)) {
            if (j < end) {  // group-uniform: finished groups issue NO memory ops
                uint4 e4 = *reinterpret_cast<const uint4*>(edges + j);
                float w0 = wdec(e4.x), w1 = wdec(e4.y), w2 = wdec(e4.z), w3 = wdec(e4.w);
                float4 r0 = ((const float4*)(hin + (size_t)(e4.x & 0x1FFFF) * 64))[c8];
                float4 r1 = ((const float4*)(hin + (size_t)(e4.y & 0x1FFFF) * 64))[c8];
                float4 r2 = ((const float4*)(hin + (size_t)(e4.z & 0x1FFFF) * 64))[c8];
                float4 r3 = ((const float4*)(hin + (size_t)(e4.w & 0x1FFFF) * 64))[c8];
                float f0[8], f1[8], f2[8], f3[8];
                unpack8(r0, f0);
                unpack8(r1, f1);
                unpack8(r2, f2);
                unpack8(r3, f3);
#pragma unroll
                for (int i = 0; i < 8; ++i) {
                    a0[i] = fmaf(w0, f0[i], a0[i]);
                    a1[i] = fmaf(w1, f1[i], a1[i]);
                    a2[i] = fmaf(w2, f2[i], a2[i]);
                    a3[i] = fmaf(w3, f3[i], a3[i]);
                }
            }
            j += 4;
        }
        float di = dinv[nd];
        float c1 = (1.0f - ALPHA) * di * di;
        float4 hs4 = ((const float4*)(hin + (size_t)nd * 64))[c8];
        float4 xs4 = ((const float4*)(x0h + (size_t)nd * 64))[c8];
        float hf[8], xf[8];
        unpack8(hs4, hf);
        unpack8(xs4, xf);
        f16x8 zv8;
#pragma unroll
        for (int i = 0; i < 8; ++i)
            zv8[i] = (f16)fmaf(ALPHA, xf[i],
                               fmaf(c1, hf[i], (a0[i] + a1[i]) + (a2[i] + a3[i])));
        *(f16x8*)(As + row * 72 + c8 * 8) = zv8;
    }
    __syncthreads();
    int lr = lane & 15, kg = lane >> 4;
    f32x4 acc0 = {0, 0, 0, 0}, acc1 = {0, 0, 0, 0}, acc2 = {0, 0, 0, 0}, acc3 = {0, 0, 0, 0};
    f16x8 af0 = *(const f16x8*)(As + (wv * 16 + lr) * 72 + kg * 8);
    f16x8 af1 = *(const f16x8*)(As + (wv * 16 + lr) * 72 + 32 + kg * 8);
    {
        f16x8 b0 = *(const f16x8*)(Bs + (0 * 16 + lr) * 72 + kg * 8);
        f16x8 b1 = *(const f16x8*)(Bs + (0 * 16 + lr) * 72 + 32 + kg * 8);
        acc0 = __builtin_amdgcn_mfma_f32_16x16x32_f16(af0, b0, acc0, 0, 0, 0);
        acc0 = __builtin_amdgcn_mfma_f32_16x16x32_f16(af1, b1, acc0, 0, 0, 0);
    }
    {
        f16x8 b0 = *(const f16x8*)(Bs + (1 * 16 + lr) * 72 + kg * 8);
        f16x8 b1 = *(const f16x8*)(Bs + (1 * 16 + lr) * 72 + 32 + kg * 8);
        acc1 = __builtin_amdgcn_mfma_f32_16x16x32_f16(af0, b0, acc1, 0, 0, 0);
        acc1 = __builtin_amdgcn_mfma_f32_16x16x32_f16(af1, b1, acc1, 0, 0, 0);
    }
    {
        f16x8 b0 = *(const f16x8*)(Bs + (2 * 16 + lr) * 72 + kg * 8);
        f16x8 b1 = *(const f16x8*)(Bs + (2 * 16 + lr) * 72 + 32 + kg * 8);
        acc2 = __builtin_amdgcn_mfma_f32_16x16x32_f16(af0, b0, acc2, 0, 0, 0);
        acc2 = __builtin_amdgcn_mfma_f32_16x16x32_f16(af1, b1, acc2, 0, 0, 0);
    }
    {
        f16x8 b0 = *(const f16x8*)(Bs + (3 * 16 + lr) * 72 + kg * 8);
        f16x8 b1 = *(const f16x8*)(Bs + (3 * 16 + lr) * 72 + 32 + kg * 8);
        acc3 = __builtin_amdgcn_mfma_f32_16x16x32_f16(af0, b0, acc3, 0, 0, 0);
        acc3 = __builtin_amdgcn_mfma_f32_16x16x32_f16(af1, b1, acc3, 0, 0, 0);
    }
    float omb = 1.0f - beta;
    f16 ov[4][4];
#pragma unroll
    for (int cg = 0; cg < 4; ++cg) {
        f32x4 acc = (cg == 0) ? acc0 : (cg == 1) ? acc1 : (cg == 2) ? acc2 : acc3;
        int col = cg * 16 + lr;
#pragma unroll
        for (int r = 0; r < 4; ++r) {
            float zv = (float)As[(wv * 16 + kg * 4 + r) * 72 + col];
            ov[cg][r] = (f16)fmaxf(fmaf(beta, acc[r], omb * zv), 0.f);
        }
    }
    __syncthreads();
#pragma unroll
    for (int cg = 0; cg < 4; ++cg)
#pragma unroll
        for (int r = 0; r < 4; ++r)
            As[(wv * 16 + kg * 4 + r) * 72 + cg * 16 + lr] = ov[cg][r];
    __syncthreads();

    if (!Wout) {
#pragma unroll
        for (int it = 0; it < 2; ++it) {
            int idx = t + it * 256;
            int rw = idx >> 3, ch = idx & 7;
            int node = node0 + rw;
            if (node < n)
                ((float4*)(hout + (size_t)node * 64))[ch] =
                    *reinterpret_cast<const float4*>(As + rw * 72 + ch * 8);
        }
    } else {
        // last layer: fused out = h @ W_out + b_out via second MFMA pass
        for (int i = t; i < 32 * 64; i += 256) {
            int c = i >> 6, k = i & 63;
            Bs[c * 72 + k] = (c < NOUT) ? (f16)Wout[k * NOUT + c] : (f16)0.0f;
        }
        __syncthreads();
        f16x8 ha0 = *(const f16x8*)(As + (wv * 16 + lr) * 72 + kg * 8);
        f16x8 ha1 = *(const f16x8*)(As + (wv * 16 + lr) * 72 + 32 + kg * 8);
#pragma unroll
        for (int ct = 0; ct < 2; ++ct) {
            f32x4 oacc = {0, 0, 0, 0};
            f16x8 b0 = *(const f16x8*)(Bs + (ct * 16 + lr) * 72 + kg * 8);
            f16x8 b1 = *(const f16x8*)(Bs + (ct * 16 + lr) * 72 + 32 + kg * 8);
            oacc = __builtin_amdgcn_mfma_f32_16x16x32_f16(ha0, b0, oacc, 0, 0, 0);
            oacc = __builtin_amdgcn_mfma_f32_16x16x32_f16(ha1, b1, oacc, 0, 0, 0);
            int col = ct * 16 + lr;
            if (col < NOUT) {
                float bo = bout[col];
#pragma unroll
                for (int r = 0; r < 4; ++r) {
                    int nd2 = node0 + wv * 16 + kg * 4 + r;
                    if (nd2 < n) out[(size_t)nd2 * NOUT + col] = oacc[r] + bo;
                }
            }
        }
    }
}

extern "C" void kernel_launch(void* const* d_in, const int* in_sizes, int n_in,
                              void* d_out, int out_size, void* d_ws, size_t ws_size,
                              hipStream_t stream) {
    const float* x    = (const float*)d_in[0];
    const int*   ei   = (const int*)d_in[1];
    const float* ew   = (const float*)d_in[2];
    const float* Win  = (const float*)d_in[3];
    const float* bin  = (const float*)d_in[4];
    const float* cw   = (const float*)d_in[5];
    const float* Wout = (const float*)d_in[6];
    const float* bout = (const float*)d_in[7];

    const int n = in_sizes[0] / FIN;          // 100000
    const int e = in_sizes[2];                // 1600000
    const int L = in_sizes[5] / (HID * HID);  // 8
    const int* row = ei;
    const int* col = ei + e;
    const int epadmax = e + 3 * n + 64;

    size_t off = 0;
    auto alloc = [&](size_t bytes) -> char* {
        char* q = (char*)d_ws + off;
        off = (off + bytes + 255) & ~(size_t)255;
        return q;
    };
    __half* x0h  = (__half*)alloc((size_t)n * HID * 2);
    __half* hA   = (__half*)alloc((size_t)n * HID * 2);
    __half* hB   = (__half*)alloc((size_t)n * HID * 2);
    unsigned* edges = (unsigned*)alloc((size_t)epadmax * 4);
    uint2* rec   = (uint2*)alloc((size_t)e * 8);
    unsigned* packed = (unsigned*)alloc((size_t)n * 4);
    float* dinv  = (float*)alloc((size_t)n * 4);
    int*   padcnt= (int*)alloc((size_t)n * 4);
    int*   rp    = (int*)alloc((size_t)(n + 1) * 4);
    int*   bsum  = (int*)alloc(1024 * 4);
    f16*   Wt    = (f16*)alloc((size_t)64 * 320 * 2);

    const int nb = (n + 1023) / 1024;
    const int ntile = (n + 63) / 64;

    hipMemsetAsync(packed, 0, (size_t)n * 4, stream);
    wt_k<<<(64 * 320 + 255) / 256, 256, 0, stream>>>(Win, Wt);
    accum_k<<<(e + 255) / 256, 256, 0, stream>>>(row, col, ew, packed, rec, e);
    unpackscan_k<<<nb, 1024, 0, stream>>>(packed, dinv, padcnt, bsum, n);
    scan2_k<<<1, 64, 0, stream>>>(bsum, nb, rp, n);
    scan3_k<<<nb, 1024, 0, stream>>>(padcnt, packed, bsum, rp, edges, n);

    fgi_k<<<FBLK + ntile, 256, 0, stream>>>(rec, dinv, rp, edges, e,
                                            x, Wt, bin, x0h, n);

    const __half* hin = x0h;
    __half* hout = hA;
    for (int l = 0; l < L; ++l) {
        float beta = (float)log(0.5 / (double)(l + 1) + 1.0);
        bool last = (l == L - 1);
        layer_k<<<ntile, 256, 0, stream>>>(rp, edges, dinv, x0h, hin, hout,
                                           cw + (size_t)l * HID * HID, beta, n,
                                           last ? Wout : nullptr,
                                           last ? bout : nullptr,
                                           last ? (float*)d_out : nullptr);
        hin = hout;
        hout = (hout == hA) ? hB : hA;
    }
}